// Round 2
// baseline (599.698 us; speedup 1.0000x reference)
//
#include <hip/hip_runtime.h>

// VectorQuantizer: x (32,64,64,64) f32, codebook (1024,64) f32
// out = concat( quantized (32,64,64,64) f32 , indices (32,64,64) as f32 )
//
// R2: remat-proof compute structure. R1's compiler kept only 64 VGPRs and
// re-loaded x[64] from global inside the K loop (VALUBusy 36%). Now each
// thread holds 32 distance accumulators (one K-tile); per dim-chunk, 4
// x-loads feed 128 FMAs, so reloading is harmless by construction.
// Codebook tiles (32 rows = 8 KB) staged in LDS, double-buffered; reads are
// wave-uniform -> LDS broadcast, no bank conflicts.

#define VQ_D   64
#define VQ_K   1024
#define VQ_HW  4096        // 64*64 spatial per batch
#define VQ_B   32
#define VQ_NPOS (VQ_B * VQ_HW)   // 131072
#define TK     32          // codes per LDS tile
#define NT     (VQ_K / TK) // 32 tiles

__global__ __launch_bounds__(256, 2)
void vq_argmin_kernel(const float* __restrict__ x,
                      const float* __restrict__ cb,
                      float* __restrict__ out,       // (B,D,H,W)
                      float* __restrict__ idx_out)   // (B,H,W) as float
{
    __shared__ float  cbn[VQ_K];          // 4 KB
    __shared__ float4 tile[2][TK * 16];   // 2 x 8 KB, row-major [code][dchunk]

    const int tid = threadIdx.x;

    // ---- codebook norms into LDS (once per block) ----
    for (int k = tid; k < VQ_K; k += 256) {
        const float4* row = (const float4*)(cb + k * VQ_D);
        float a0 = 0.f, a1 = 0.f, a2 = 0.f, a3 = 0.f;
        #pragma unroll
        for (int j = 0; j < 16; ++j) {
            float4 c = row[j];
            a0 = fmaf(c.x, c.x, a0);
            a1 = fmaf(c.y, c.y, a1);
            a2 = fmaf(c.z, c.z, a2);
            a3 = fmaf(c.w, c.w, a3);
        }
        cbn[k] = (a0 + a1) + (a2 + a3);
    }

    // ---- stage tile 0 (8 KB contiguous memcpy: 2 float4 per thread) ----
    {
        const float4* s0 = (const float4*)cb;
        float4 q0 = s0[tid];
        float4 q1 = s0[tid + 256];
        tile[0][tid]       = q0;
        tile[0][tid + 256] = q1;
    }

    const int p = blockIdx.x * 256 + tid;     // global position
    const int b = p >> 12;                    // 4096 positions per batch
    const int n = p & (VQ_HW - 1);
    const float* xp = x + (size_t)b * (VQ_D * VQ_HW) + n;

    float best  = 3.4e38f;
    int   bestk = 0;

    __syncthreads();

    for (int t = 0; t < NT; ++t) {
        const int cur = t & 1;

        // prefetch next tile into registers (completes during compute)
        float4 q0, q1;
        if (t + 1 < NT) {
            const float4* s = (const float4*)(cb + (size_t)(t + 1) * TK * VQ_D);
            q0 = s[tid];
            q1 = s[tid + 256];
        }

        float acc[TK];
        #pragma unroll
        for (int c = 0; c < TK; ++c) acc[c] = 0.f;

        const float4* tb = tile[cur];
        for (int dc = 0; dc < 16; ++dc) {
            // 4 coalesced x loads feed 128 FMAs -> remat harmless
            const float xd0 = xp[(dc * 4 + 0) * VQ_HW];
            const float xd1 = xp[(dc * 4 + 1) * VQ_HW];
            const float xd2 = xp[(dc * 4 + 2) * VQ_HW];
            const float xd3 = xp[(dc * 4 + 3) * VQ_HW];
            #pragma unroll
            for (int c = 0; c < TK; ++c) {
                float4 cv = tb[c * 16 + dc];   // wave-uniform -> LDS broadcast
                acc[c] = fmaf(xd0, cv.x, acc[c]);
                acc[c] = fmaf(xd1, cv.y, acc[c]);
                acc[c] = fmaf(xd2, cv.z, acc[c]);
                acc[c] = fmaf(xd3, cv.w, acc[c]);
            }
        }

        // argmin update; ascending k + strict < == jnp.argmin first-min
        const int k0 = t * TK;
        #pragma unroll
        for (int c = 0; c < TK; ++c) {
            const float dist = cbn[k0 + c] - 2.0f * acc[c];
            if (dist < best) { best = dist; bestk = k0 + c; }
        }

        // write prefetched tile into the other buffer, then barrier
        if (t + 1 < NT) {
            float4* nb = tile[cur ^ 1];
            nb[tid]       = q0;
            nb[tid + 256] = q1;
        }
        __syncthreads();
    }

    // ---- epilogue: gather winning row, scatter to (B,D,H,W) layout ----
    float* op = out + (size_t)b * (VQ_D * VQ_HW) + n;
    const float* wrow = cb + (size_t)bestk * VQ_D;
    #pragma unroll
    for (int d = 0; d < VQ_D; ++d) op[d * VQ_HW] = wrow[d];

    idx_out[p] = (float)bestk;
}

extern "C" void kernel_launch(void* const* d_in, const int* in_sizes, int n_in,
                              void* d_out, int out_size, void* d_ws, size_t ws_size,
                              hipStream_t stream) {
    const float* x  = (const float*)d_in[0];
    const float* cb = (const float*)d_in[1];
    float* out = (float*)d_out;
    float* idx = out + (size_t)VQ_B * VQ_D * VQ_HW;   // 8,388,608 floats in

    vq_argmin_kernel<<<dim3(VQ_NPOS / 256), dim3(256), 0, stream>>>(x, cb, out, idx);
}

// Round 3
// 359.765 us; speedup vs baseline: 1.6669x; 1.6669x over previous
//
#include <hip/hip_runtime.h>

// VectorQuantizer: x (32,64,64,64) f32, codebook (1024,64) f32
// out = concat( quantized (32,64,64,64) f32 , indices (32,64,64) as f32 )
//
// R3: lanes = codes, positions wave-uniform.
//  - R2 post-mortem: LDS broadcast b128 is ~12 cyc/wave (return BW), one DS
//    pipe per CU serves 8 waves -> DS-bound at ~600 us. So: NO LDS in hot loop.
//  - x loads are wave-uniform (base readfirstlane'd) -> compiler emits s_load;
//    x value is the SGPR operand of v_fmac (scalar pipe, free).
//  - codebook pre-transposed into d_ws as cbT4[j4][k] so lane c (code t*64+c)
//    does one coalesced float4 load per 4 dims; L1-resident, prefetched.
//  - per k-tile per wave: 1024 FMA instrs, 16 VMEM, ~64 SMEM, 0 DS.

#define VQ_D    64
#define VQ_K    1024
#define VQ_HW   4096
#define VQ_B    32
#define VQ_NPOS (VQ_B * VQ_HW)            // 131072
#define WS_CBN  65536                     // float offset of cbn[] in ws

// ---------- prep: transpose codebook + norms into workspace ----------
// ws: [0 .. 16384) float4  : cbT4[j4][k]  (j4 = dim/4, k = code)
//     [65536 .. 66560) f32 : cbn[k]
__global__ __launch_bounds__(256)
void vq_prep(const float* __restrict__ cb, float* __restrict__ ws)
{
    const int t = blockIdx.x * 256 + threadIdx.x;
    if (blockIdx.x < 64) {
        // t in [0,16384): k = t>>4, j4 = t&15 ; reads coalesced (consecutive float4)
        const int k = t >> 4, j4 = t & 15;
        const float4 v = ((const float4*)cb)[k * 16 + j4];
        ((float4*)ws)[j4 * 1024 + k] = v;
    } else {
        const int k = t - 64 * 256;       // [0,1024)
        const float4* row = (const float4*)(cb + k * VQ_D);
        float a0 = 0.f, a1 = 0.f, a2 = 0.f, a3 = 0.f;
        #pragma unroll
        for (int j = 0; j < 16; ++j) {
            float4 c = row[j];
            a0 = fmaf(c.x, c.x, a0);
            a1 = fmaf(c.y, c.y, a1);
            a2 = fmaf(c.z, c.z, a2);
            a3 = fmaf(c.w, c.w, a3);
        }
        ws[WS_CBN + k] = (a0 + a1) + (a2 + a3);
    }
}

// ---------- main ----------
__global__ __launch_bounds__(256)
void vq_main(const float* __restrict__ x,
             const float* __restrict__ cb,
             const float* __restrict__ ws,
             float* __restrict__ out,
             float* __restrict__ idx_out)
{
    __shared__ int lds_k[64];

    const int tid  = threadIdx.x;
    const int lane = tid & 63;
    const int wv   = tid >> 6;            // wave id in block, 0..3

    const float4* cbT4 = (const float4*)ws;
    const float*  cbn  = ws + WS_CBN;

    // wave handles 16 consecutive positions; base forced wave-uniform
    const int p0 = __builtin_amdgcn_readfirstlane(blockIdx.x * 64 + wv * 16);
    const int b  = p0 >> 12;              // 4096 positions per batch
    const int n0 = p0 & (VQ_HW - 1);
    const float* xw = x + (size_t)b * (VQ_D * VQ_HW) + n0;   // uniform base

    float best[16];
    int   bestk[16];
    #pragma unroll
    for (int m = 0; m < 16; ++m) { best[m] = 3.4e38f; bestk[m] = 0; }

    float4 cv_next = cbT4[lane];          // (t=0,j4=0): j4*1024 + t*64 + lane

    for (int t = 0; t < 16; ++t) {
        const int code = t * 64 + lane;   // this lane's code in this tile
        const float cn = cbn[code];       // coalesced dword, used at tile end

        float acc[16];
        #pragma unroll
        for (int m = 0; m < 16; ++m) acc[m] = 0.f;

        #pragma unroll 4
        for (int j4 = 0; j4 < 16; ++j4) {
            const float4 cv = cv_next;
            // prefetch next (flat t,j4) tile element (clamped; extra load harmless)
            {
                int flat = t * 16 + j4 + 1;
                if (flat > 255) flat = 255;
                const int tn  = flat >> 4;
                const int j4n = flat & 15;
                cv_next = cbT4[j4n * 1024 + tn * 64 + lane];
            }
            // x rows for dims 4*j4 .. 4*j4+3 : wave-uniform -> s_load
            const float* xr0 = xw + (j4 * 4 + 0) * VQ_HW;
            const float* xr1 = xw + (j4 * 4 + 1) * VQ_HW;
            const float* xr2 = xw + (j4 * 4 + 2) * VQ_HW;
            const float* xr3 = xw + (j4 * 4 + 3) * VQ_HW;
            #pragma unroll
            for (int m = 0; m < 16; ++m) {
                acc[m] = fmaf(cv.x, xr0[m], acc[m]);
                acc[m] = fmaf(cv.y, xr1[m], acc[m]);
                acc[m] = fmaf(cv.z, xr2[m], acc[m]);
                acc[m] = fmaf(cv.w, xr3[m], acc[m]);
            }
        }

        // dist = ||c||^2 - 2 x.c ; ascending code + strict < = first-min
        #pragma unroll
        for (int m = 0; m < 16; ++m) {
            const float dist = cn - 2.0f * acc[m];
            if (dist < best[m]) { best[m] = dist; bestk[m] = code; }
        }
    }

    // cross-lane argmin per position: min dist, tie -> min index (jnp first-min)
    #pragma unroll
    for (int m = 0; m < 16; ++m) {
        float d = best[m];
        int   k = bestk[m];
        #pragma unroll
        for (int off = 32; off > 0; off >>= 1) {
            const float od = __shfl_xor(d, off, 64);
            const int   ok = __shfl_xor(k, off, 64);
            if (od < d || (od == d && ok < k)) { d = od; k = ok; }
        }
        if (lane == 0) lds_k[wv * 16 + m] = k;
    }
    __syncthreads();

    // ---- epilogue: block covers 64 consecutive positions (same batch) ----
    const int pb  = blockIdx.x * 64;
    const int bb  = pb >> 12;
    const int nb  = pb & (VQ_HW - 1);
    const int i   = tid & 63;             // position within block
    const int dg  = tid >> 6;             // dim group 0..3 (16 dims each)
    const int bk  = lds_k[i];

    const float4* cbr = (const float4*)(cb + (size_t)bk * VQ_D);
    float* ob = out + (size_t)bb * (VQ_D * VQ_HW) + nb + i;
    #pragma unroll
    for (int q = 0; q < 4; ++q) {
        const float4 v = cbr[dg * 4 + q]; // gather (per-lane row), L1/L2-hot
        const int d0 = dg * 16 + q * 4;
        ob[(size_t)(d0 + 0) * VQ_HW] = v.x;   // coalesced over i
        ob[(size_t)(d0 + 1) * VQ_HW] = v.y;
        ob[(size_t)(d0 + 2) * VQ_HW] = v.z;
        ob[(size_t)(d0 + 3) * VQ_HW] = v.w;
    }
    if (tid < 64) idx_out[pb + tid] = (float)lds_k[tid];
}

extern "C" void kernel_launch(void* const* d_in, const int* in_sizes, int n_in,
                              void* d_out, int out_size, void* d_ws, size_t ws_size,
                              hipStream_t stream) {
    const float* x  = (const float*)d_in[0];
    const float* cb = (const float*)d_in[1];
    float* out = (float*)d_out;
    float* idx = out + (size_t)VQ_B * VQ_D * VQ_HW;   // 8,388,608 floats in
    float* ws  = (float*)d_ws;                         // needs 67,584 floats (~264 KB)

    vq_prep<<<dim3(68), dim3(256), 0, stream>>>(cb, ws);
    vq_main<<<dim3(VQ_NPOS / 64), dim3(256), 0, stream>>>(x, cb, ws, out, idx);
}

// Round 4
// 175.154 us; speedup vs baseline: 3.4238x; 2.0540x over previous
//
#include <hip/hip_runtime.h>

// VectorQuantizer: x (32,64,64,64) f32, codebook (1024,64) f32
// out = concat( quantized (32,64,64,64) f32 , indices (32,64,64) as f32 )
//
// R4: MFMA path. f32 = hi_f16 + lo_f16/2048 (lo scaled to avoid f16 denorm
// flush). dot = hihi + (hilo + lohi)/2048; dropped lolo term -> dist error
// <= ~3e-4. Top-2 tracking flags positions with gap < 2e-3 for an exact-f32
// rescan kernel (expected <1% of positions), guaranteeing jnp-first-min
// agreement. MFMA floor ~25 us vs the 109 us f32 VALU wall R1-R3 fought.
//
// Verified layouts (learn_hip m89/m91/m120): mfma_f32_16x16x32_f16
//   A: lane holds A[m=lane&15][k=(lane>>4)*8+j], j=0..7
//   B: lane holds B[k=(lane>>4)*8+j][n=lane&15]
//   C/D: col=lane&15, row=(lane>>4)*4+reg

typedef _Float16 f16x8 __attribute__((ext_vector_type(8)));
typedef float    f32x4 __attribute__((ext_vector_type(4)));

#define VQ_D    64
#define VQ_HW   4096
#define VQ_B    32
#define VQ_NPOS (VQ_B * VQ_HW)     // 131072
#define WS_CBN  65536              // float offset: cbn[1024]
#define WS_CNT  66560              // int offset: rescan counter
#define WS_LIST 66564              // int offset: rescan list[131072]
#define EPS     2.0e-3f
#define SC      2048.0f
#define ISC     (1.0f / 2048.0f)

__device__ inline void split16(float v, _Float16& h, _Float16& l) {
    h = (_Float16)v;
    l = (_Float16)((v - (float)h) * SC);
}

// ---------- prep: pack B-fragments (hi/lo) + cbn + zero counter ----------
// bpk layout: f16x8 index ((ct*2+ks)*2+h)*64 + lane ; ct<64, ks<2, h in {hi,lo}
__global__ __launch_bounds__(256)
void vq_prep(const float* __restrict__ cb, float* __restrict__ ws)
{
    const int tid = threadIdx.x;
    if (blockIdx.x < 16) {
        const int gt   = blockIdx.x * 256 + tid;   // [0,4096)
        const int ct   = gt >> 6;
        const int lane = gt & 63;
        const int n    = ct * 16 + (lane & 15);
        const int quad = lane >> 4;
        f16x8* bpk = (f16x8*)ws;
        #pragma unroll
        for (int ks = 0; ks < 2; ++ks) {
            const int k0 = ks * 32 + quad * 8;
            f16x8 h8, l8;
            #pragma unroll
            for (int j = 0; j < 8; ++j) {
                float v = cb[n * 64 + k0 + j];
                _Float16 h, l; split16(v, h, l);
                h8[j] = h; l8[j] = l;
            }
            bpk[((ct * 2 + ks) * 2 + 0) * 64 + lane] = h8;
            bpk[((ct * 2 + ks) * 2 + 1) * 64 + lane] = l8;
        }
    } else {
        const int k = (blockIdx.x - 16) * 256 + tid;  // [0,1024)
        const float4* row = (const float4*)(cb + k * 64);
        float a0 = 0.f, a1 = 0.f, a2 = 0.f, a3 = 0.f;
        #pragma unroll
        for (int j = 0; j < 16; ++j) {
            float4 c = row[j];
            a0 = fmaf(c.x, c.x, a0); a1 = fmaf(c.y, c.y, a1);
            a2 = fmaf(c.z, c.z, a2); a3 = fmaf(c.w, c.w, a3);
        }
        ws[WS_CBN + k] = (a0 + a1) + (a2 + a3);
        if (k == 0) ((int*)ws)[WS_CNT] = 0;
    }
}

// ---------- main: MFMA argmin ----------
__global__ __launch_bounds__(256)
void vq_mfma(const float* __restrict__ x,
             const float* __restrict__ cb,
             float* __restrict__ ws,
             float* __restrict__ out,
             float* __restrict__ idx_out)
{
    __shared__ int   sk[128];
    __shared__ float smg[128];

    const int tid  = threadIdx.x;
    const int lane = tid & 63;
    const int wv   = tid >> 6;

    const f16x8* bpk = (const f16x8*)ws;
    const float* cbn = ws + WS_CBN;

    // wave owns 32 consecutive positions (two 16-row M-tiles)
    const int p0 = blockIdx.x * 128 + wv * 32;
    const int b  = p0 >> 12;
    const int n0 = p0 & (VQ_HW - 1);
    const float* xw = x + (size_t)b * (VQ_D * VQ_HW) + n0;

    const int m  = lane & 15;
    const int kq = (lane >> 4) * 8;

    // ---- A-fragments (hi/lo), resident for the whole K loop ----
    f16x8 Ah[2][2], Al[2][2];          // [tile][ks]
    #pragma unroll
    for (int tl = 0; tl < 2; ++tl)
        #pragma unroll
        for (int ks = 0; ks < 2; ++ks) {
            f16x8 h8, l8;
            #pragma unroll
            for (int j = 0; j < 8; ++j) {
                const int k = ks * 32 + kq + j;
                float v = xw[(size_t)k * VQ_HW + tl * 16 + m];
                _Float16 h, l; split16(v, h, l);
                h8[j] = h; l8[j] = l;
            }
            Ah[tl][ks] = h8; Al[tl][ks] = l8;
        }

    float d1[2][4], d2[2][4]; int k1[2][4];
    #pragma unroll
    for (int tl = 0; tl < 2; ++tl)
        #pragma unroll
        for (int r = 0; r < 4; ++r) { d1[tl][r] = 3.4e38f; d2[tl][r] = 3.4e38f; k1[tl][r] = 0; }

    // preload B frags for ct=0
    f16x8 Bh[2], Bl[2];
    #pragma unroll
    for (int ks = 0; ks < 2; ++ks) {
        Bh[ks] = bpk[((0 * 2 + ks) * 2 + 0) * 64 + lane];
        Bl[ks] = bpk[((0 * 2 + ks) * 2 + 1) * 64 + lane];
    }

    for (int ct = 0; ct < 64; ++ct) {
        // prefetch next code tile's B fragments
        f16x8 nBh[2], nBl[2];
        const int ctn = (ct < 63) ? ct + 1 : 63;
        #pragma unroll
        for (int ks = 0; ks < 2; ++ks) {
            nBh[ks] = bpk[((ctn * 2 + ks) * 2 + 0) * 64 + lane];
            nBl[ks] = bpk[((ctn * 2 + ks) * 2 + 1) * 64 + lane];
        }

        f32x4 acm[2] = {{0.f,0.f,0.f,0.f},{0.f,0.f,0.f,0.f}};
        f32x4 acc[2] = {{0.f,0.f,0.f,0.f},{0.f,0.f,0.f,0.f}};
        #pragma unroll
        for (int tl = 0; tl < 2; ++tl)
            #pragma unroll
            for (int ks = 0; ks < 2; ++ks) {
                acm[tl] = __builtin_amdgcn_mfma_f32_16x16x32_f16(Ah[tl][ks], Bh[ks], acm[tl], 0, 0, 0);
                acc[tl] = __builtin_amdgcn_mfma_f32_16x16x32_f16(Ah[tl][ks], Bl[ks], acc[tl], 0, 0, 0);
                acc[tl] = __builtin_amdgcn_mfma_f32_16x16x32_f16(Al[tl][ks], Bh[ks], acc[tl], 0, 0, 0);
            }

        const int code = ct * 16 + m;       // this lane's column (code)
        const float cn = cbn[code];
        #pragma unroll
        for (int tl = 0; tl < 2; ++tl)
            #pragma unroll
            for (int r = 0; r < 4; ++r) {
                const float dot  = fmaf(acc[tl][r], ISC, acm[tl][r]);
                const float dist = fmaf(-2.0f, dot, cn);
                if (dist < d1[tl][r]) { d2[tl][r] = d1[tl][r]; d1[tl][r] = dist; k1[tl][r] = code; }
                else if (dist < d2[tl][r]) d2[tl][r] = dist;
            }

        #pragma unroll
        for (int ks = 0; ks < 2; ++ks) { Bh[ks] = nBh[ks]; Bl[ks] = nBl[ks]; }
    }

    // ---- top-2 merge across the 16 lanes sharing rows (xor 1,2,4,8) ----
    #pragma unroll
    for (int off = 1; off < 16; off <<= 1) {
        #pragma unroll
        for (int tl = 0; tl < 2; ++tl)
            #pragma unroll
            for (int r = 0; r < 4; ++r) {
                const float od1 = __shfl_xor(d1[tl][r], off, 64);
                const float od2 = __shfl_xor(d2[tl][r], off, 64);
                const int   ok1 = __shfl_xor(k1[tl][r], off, 64);
                const float nd2 = fminf(fmaxf(d1[tl][r], od1), fminf(d2[tl][r], od2));
                if (od1 < d1[tl][r] || (od1 == d1[tl][r] && ok1 < k1[tl][r])) {
                    d1[tl][r] = od1; k1[tl][r] = ok1;
                }
                d2[tl][r] = nd2;
            }
    }

    if (m == 0) {                           // lanes 0,16,32,48: quad q owns rows q*4+r
        const int q = lane >> 4;
        #pragma unroll
        for (int tl = 0; tl < 2; ++tl)
            #pragma unroll
            for (int r = 0; r < 4; ++r) {
                const int li = wv * 32 + tl * 16 + q * 4 + r;
                sk[li]  = k1[tl][r];
                smg[li] = d2[tl][r] - d1[tl][r];
            }
    }
    __syncthreads();

    // ---- epilogue: indices + rescan flags + quantized scatter ----
    const int pb = blockIdx.x * 128;
    if (tid < 128) {
        const int p = pb + tid;
        idx_out[p] = (float)sk[tid];
        if (smg[tid] < EPS) {
            const int slot = atomicAdd((int*)ws + WS_CNT, 1);
            ((int*)ws)[WS_LIST + slot] = p;
        }
    }
    const int i    = tid & 127;
    const int half = tid >> 7;              // dims [0,32) or [32,64)
    const int bk   = sk[i];
    const float4* cr = (const float4*)(cb + (size_t)bk * VQ_D) + half * 8;
    float* ob = out + (size_t)(pb >> 12) * (VQ_D * VQ_HW) + (pb & (VQ_HW - 1)) + i;
    #pragma unroll
    for (int q8 = 0; q8 < 8; ++q8) {
        const float4 v = cr[q8];
        const int d0 = half * 32 + q8 * 4;
        ob[(size_t)(d0 + 0) * VQ_HW] = v.x;
        ob[(size_t)(d0 + 1) * VQ_HW] = v.y;
        ob[(size_t)(d0 + 2) * VQ_HW] = v.z;
        ob[(size_t)(d0 + 3) * VQ_HW] = v.w;
    }
}

// ---------- rescan: exact f32 argmin for flagged positions ----------
__global__ __launch_bounds__(64)
void vq_rescan(const float* __restrict__ x,
               const float* __restrict__ cb,
               const float* __restrict__ ws,
               float* __restrict__ out,
               float* __restrict__ idx_out)
{
    __shared__ float xs[VQ_D];
    const int lane = threadIdx.x;
    const int cnt  = ((const int*)ws)[WS_CNT];
    const int* list = (const int*)ws + WS_LIST;
    const float* cbn = ws + WS_CBN;

    for (int i = blockIdx.x; i < cnt; i += gridDim.x) {
        const int p = list[i];
        const int b = p >> 12, n = p & (VQ_HW - 1);
        xs[lane] = x[(size_t)b * (VQ_D * VQ_HW) + (size_t)lane * VQ_HW + n];
        __syncthreads();
        const float4* xs4 = (const float4*)xs;
        float best = 3.4e38f; int bk = 0;
        for (int t = 0; t < 16; ++t) {
            const int code = t * 64 + lane;              // per-lane ascending
            const float4* crow = (const float4*)(cb + (size_t)code * VQ_D);
            float a0 = 0.f, a1 = 0.f, a2 = 0.f, a3 = 0.f;
            #pragma unroll
            for (int d4 = 0; d4 < 16; ++d4) {
                const float4 c  = crow[d4];
                const float4 xv = xs4[d4];
                a0 = fmaf(xv.x, c.x, a0); a1 = fmaf(xv.y, c.y, a1);
                a2 = fmaf(xv.z, c.z, a2); a3 = fmaf(xv.w, c.w, a3);
            }
            const float dist = fmaf(-2.0f, (a0 + a1) + (a2 + a3), cbn[code]);
            if (dist < best) { best = dist; bk = code; }
        }
        #pragma unroll
        for (int off = 1; off < 64; off <<= 1) {         // min dist, tie -> min k
            const float od = __shfl_xor(best, off, 64);
            const int   ok = __shfl_xor(bk, off, 64);
            if (od < best || (od == best && ok < bk)) { best = od; bk = ok; }
        }
        out[(size_t)b * (VQ_D * VQ_HW) + (size_t)lane * VQ_HW + n] = cb[(size_t)bk * VQ_D + lane];
        if (lane == 0) idx_out[p] = (float)bk;
        __syncthreads();
    }
}

extern "C" void kernel_launch(void* const* d_in, const int* in_sizes, int n_in,
                              void* d_out, int out_size, void* d_ws, size_t ws_size,
                              hipStream_t stream) {
    const float* x  = (const float*)d_in[0];
    const float* cb = (const float*)d_in[1];
    float* out = (float*)d_out;
    float* idx = out + (size_t)VQ_NPOS * VQ_D;   // 8,388,608 floats in
    float* ws  = (float*)d_ws;                    // ~790 KB used

    vq_prep  <<<dim3(20),            dim3(256), 0, stream>>>(cb, ws);
    vq_mfma  <<<dim3(VQ_NPOS / 128), dim3(256), 0, stream>>>(x, cb, ws, out, idx);
    vq_rescan<<<dim3(1024),          dim3(64),  0, stream>>>(x, cb, ws, out, idx);
}